// Round 9
// baseline (47.766 us; speedup 1.0000x reference)
//
#include <hip/hip_runtime.h>

// Plenoxels: trilinear voxel interp (192^3 x 28 ch) + SH deg-2 eval.
// R9: fused kernel, deeper MLP.
//  - 4 tiles (1024 pts) per block pooled into one 32KB LDS record pool
//    -> ~21 chunks per block, ~5 per wave (was 1.3), 4x fewer barriers/pt.
//  - phase 2 branch-free + PAIR-UNROLLED: each wave runs chunks c and c+4
//    per iteration, 14 scattered cell-loads in flight (was 7). Clamped
//    record reads + predicated stores handle the ragged tail.
//  - idx (ix,iy,iz) computed once in phase 1, stored in the record.
// Gather / SH / DPP reduce semantics identical to validated R8.

#define VNL 192
#define BLK 256
#define WPB 4
#define TILES 4
#define PTS (BLK * TILES)

#define SH_C0f 0.28209479177387814f
#define SH_C1f 0.4886025119029199f
#define C2_0f  1.0925484305920792f
#define C2_1f (-1.0925484305920792f)
#define C2_2f  0.31539156525252005f
#define C2_3f (-1.0925484305920792f)
#define C2_4f  0.5462742152960396f

template <int CTRL>
__device__ __forceinline__ float dpp_add(float v) {
    int s = __builtin_amdgcn_update_dpp(0, __float_as_int(v), CTRL, 0xF, 0xF, true);
    return v + __int_as_float(s);
}

__global__ __launch_bounds__(BLK) void plen_fused_kernel(
    const float* __restrict__ x,
    const float* __restrict__ d,
    const float* __restrict__ voxel,
    float* __restrict__ out,
    int N)
{
    __shared__ __align__(16) float4 s_pool[PTS][2];   // 32 KB record pool
    __shared__ unsigned s_wcnt[WPB];

    const int tid  = threadIdx.x;
    const int wid  = tid >> 6;
    const int lane = tid & 63;
    const int g = lane >> 3;   // group 0..7
    const int j = lane & 7;    // corner 0..7
    const int base_i = blockIdx.x * PTS;

    // ---- phase 1: mask, zero inactive, pool records over 4 tiles ----------
    unsigned Mrun = 0;
    for (int t = 0; t < TILES; ++t) {
        int i = base_i + t * BLK + tid;
        bool act = false;
        float ix = 0.f, iy = 0.f, iz = 0.f;
        float vdx = 0.f, vdy = 0.f, vdz = 0.f;
        if (i < N) {
            float px = x[3 * i + 0] / 1.5f;
            float py = x[3 * i + 1] / 1.5f;
            float pz = x[3 * i + 2] / 1.5f;
            act = (fabsf(px) < 0.5f) && (fabsf(py) < 0.5f) && (fabsf(pz) < 0.5f);
            vdx = d[3 * i + 0];
            vdy = d[3 * i + 1];
            vdz = d[3 * i + 2];
            if (act) {
                const float step = 2.0f / (float)VNL;
                ix = fminf(fmaxf(px / step + (float)(VNL / 2), 0.0f), (float)(VNL - 1));
                iy = fminf(fmaxf(py / step + (float)(VNL / 2), 0.0f), (float)(VNL - 1));
                iz = fminf(fmaxf(pz / step + (float)(VNL / 2), 0.0f), (float)(VNL - 1));
            } else {
                out[3 * i + 0] = 0.f;
                out[3 * i + 1] = 0.f;
                out[3 * i + 2] = 0.f;
                out[(size_t)3 * N + i] = 0.f;
            }
        }

        unsigned long long bal = __ballot(act);
        unsigned wtot = (unsigned)__popcll(bal);
        unsigned pre  = (unsigned)__popcll(bal & ((1ull << lane) - 1ull));
        if (lane == 0) s_wcnt[wid] = wtot;
        __syncthreads();
        unsigned n0 = s_wcnt[0], n1 = s_wcnt[1], n2 = s_wcnt[2], n3 = s_wcnt[3];
        unsigned wbase = Mrun + (wid > 0 ? n0 : 0u) + (wid > 1 ? n1 : 0u)
                              + (wid > 2 ? n2 : 0u);
        if (act) {
            unsigned slot = wbase + pre;
            s_pool[slot][0] = make_float4(ix, iy, iz, __int_as_float(i));
            s_pool[slot][1] = make_float4(vdx, vdy, vdz, 0.f);
        }
        Mrun += n0 + n1 + n2 + n3;
        __syncthreads();   // s_wcnt reuse next tile; record visibility
    }

    const unsigned M = Mrun;
    if (M == 0) return;
    const unsigned nch = (M + 7u) >> 3;

    // ---- phase 2: pair-unrolled branch-free gather -------------------------
    for (unsigned c = (unsigned)wid; c < nch; c += 2u * WPB) {
        unsigned cA = c;
        unsigned cB = c + WPB;                 // may exceed nch -> clamped work

        // --- chunk A: record + address + loads ---
        unsigned rA = cA * 8u + (unsigned)g;
        bool onA = (rA < M);
        unsigned rrA = onA ? rA : (M - 1u);
        float4 a0 = s_pool[rrA][0];
        float4 a1 = s_pool[rrA][1];
        float fxA = floorf(a0.x), fyA = floorf(a0.y), fzA = floorf(a0.z);
        int fA0 = (int)fxA, fA1 = (int)fyA, fA2 = (int)fzA;
        int cA0 = (int)ceilf(a0.x), cA1 = (int)ceilf(a0.y), cA2 = (int)ceilf(a0.z);
        float tA0 = a0.x - fxA, tA1 = a0.y - fyA, tA2 = a0.z - fzA;
        float wjA = ((j & 4) ? tA2 : 1.0f - tA2) * ((j & 2) ? tA1 : 1.0f - tA1)
                  * ((j & 1) ? tA0 : 1.0f - tA0);
        int XA = ((0xE2 >> j) & 1) ? cA0 : fA0;
        int YA = ((0xD4 >> j) & 1) ? cA1 : fA1;
        int ZA = ((0xB8 >> j) & 1) ? cA2 : fA2;
        const char* cellA = (const char*)voxel
            + (size_t)(unsigned)(((XA * VNL + YA) * VNL + ZA) * 112);
        float4 vA0 = *(const float4*)(cellA +  0);
        float4 vA1 = *(const float4*)(cellA + 16);
        float4 vA2 = *(const float4*)(cellA + 32);
        float4 vA3 = *(const float4*)(cellA + 48);
        float4 vA4 = *(const float4*)(cellA + 64);
        float4 vA5 = *(const float4*)(cellA + 80);
        float4 vA6 = *(const float4*)(cellA + 96);

        // --- chunk B: record + address + loads ---
        unsigned rB = cB * 8u + (unsigned)g;
        bool onB = (rB < M);
        unsigned rrB = onB ? rB : (M - 1u);
        float4 b0 = s_pool[rrB][0];
        float4 b1 = s_pool[rrB][1];
        float fxB = floorf(b0.x), fyB = floorf(b0.y), fzB = floorf(b0.z);
        int fB0 = (int)fxB, fB1 = (int)fyB, fB2 = (int)fzB;
        int cB0 = (int)ceilf(b0.x), cB1 = (int)ceilf(b0.y), cB2 = (int)ceilf(b0.z);
        float tB0 = b0.x - fxB, tB1 = b0.y - fyB, tB2 = b0.z - fzB;
        float wjB = ((j & 4) ? tB2 : 1.0f - tB2) * ((j & 2) ? tB1 : 1.0f - tB1)
                  * ((j & 1) ? tB0 : 1.0f - tB0);
        int XB = ((0xE2 >> j) & 1) ? cB0 : fB0;
        int YB = ((0xD4 >> j) & 1) ? cB1 : fB1;
        int ZB = ((0xB8 >> j) & 1) ? cB2 : fB2;
        const char* cellB = (const char*)voxel
            + (size_t)(unsigned)(((XB * VNL + YB) * VNL + ZB) * 112);
        float4 vB0 = *(const float4*)(cellB +  0);
        float4 vB1 = *(const float4*)(cellB + 16);
        float4 vB2 = *(const float4*)(cellB + 32);
        float4 vB3 = *(const float4*)(cellB + 48);
        float4 vB4 = *(const float4*)(cellB + 64);
        float4 vB5 = *(const float4*)(cellB + 80);
        float4 vB6 = *(const float4*)(cellB + 96);

        // --- consume A ---
        {
            float pdx = a1.x, pdy = a1.y, pdz = a1.z;
            float b1c = -SH_C1f * pdy;
            float b2c =  SH_C1f * pdz;
            float b3c = -SH_C1f * pdx;
            float b4c = C2_0f * pdx * pdy;
            float b5c = C2_1f * pdy * pdz;
            float b6c = C2_2f * (2.0f * pdz * pdz - pdx * pdx - pdy * pdy);
            float b7c = C2_3f * pdx * pdz;
            float b8c = C2_4f * (pdx * pdx - pdy * pdy);

            float cc0 = SH_C0f*vA0.y + b1c*vA0.z + b2c*vA0.w + b3c*vA1.x + b4c*vA1.y
                      + b5c*vA1.z + b6c*vA1.w + b7c*vA2.x + b8c*vA2.y;
            float cc1 = SH_C0f*vA2.z + b1c*vA2.w + b2c*vA3.x + b3c*vA3.y + b4c*vA3.z
                      + b5c*vA3.w + b6c*vA4.x + b7c*vA4.y + b8c*vA4.z;
            float cc2 = SH_C0f*vA4.w + b1c*vA5.x + b2c*vA5.y + b3c*vA5.z + b4c*vA5.w
                      + b5c*vA6.x + b6c*vA6.y + b7c*vA6.z + b8c*vA6.w;
            cc0 *= wjA; cc1 *= wjA; cc2 *= wjA;
            float ff0 = wjA * vA0.x;

            cc0 = dpp_add<0xB1>(cc0);  cc1 = dpp_add<0xB1>(cc1);
            cc2 = dpp_add<0xB1>(cc2);  ff0 = dpp_add<0xB1>(ff0);
            cc0 = dpp_add<0x4E>(cc0);  cc1 = dpp_add<0x4E>(cc1);
            cc2 = dpp_add<0x4E>(cc2);  ff0 = dpp_add<0x4E>(ff0);
            cc0 = dpp_add<0x141>(cc0); cc1 = dpp_add<0x141>(cc1);
            cc2 = dpp_add<0x141>(cc2); ff0 = dpp_add<0x141>(ff0);

            if (onA && j < 4) {
                int pi = __float_as_int(a0.w);
                float rv = (j == 0) ? cc0 : (j == 1) ? cc1 : (j == 2) ? cc2
                                                          : fmaxf(ff0, 0.0f);
                size_t a = (j < 3) ? ((size_t)3 * pi + j) : ((size_t)3 * N + pi);
                out[a] = rv;
            }
        }

        // --- consume B ---
        {
            float pdx = b1.x, pdy = b1.y, pdz = b1.z;
            float b1c = -SH_C1f * pdy;
            float b2c =  SH_C1f * pdz;
            float b3c = -SH_C1f * pdx;
            float b4c = C2_0f * pdx * pdy;
            float b5c = C2_1f * pdy * pdz;
            float b6c = C2_2f * (2.0f * pdz * pdz - pdx * pdx - pdy * pdy);
            float b7c = C2_3f * pdx * pdz;
            float b8c = C2_4f * (pdx * pdx - pdy * pdy);

            float cc0 = SH_C0f*vB0.y + b1c*vB0.z + b2c*vB0.w + b3c*vB1.x + b4c*vB1.y
                      + b5c*vB1.z + b6c*vB1.w + b7c*vB2.x + b8c*vB2.y;
            float cc1 = SH_C0f*vB2.z + b1c*vB2.w + b2c*vB3.x + b3c*vB3.y + b4c*vB3.z
                      + b5c*vB3.w + b6c*vB4.x + b7c*vB4.y + b8c*vB4.z;
            float cc2 = SH_C0f*vB4.w + b1c*vB5.x + b2c*vB5.y + b3c*vB5.z + b4c*vB5.w
                      + b5c*vB6.x + b6c*vB6.y + b7c*vB6.z + b8c*vB6.w;
            cc0 *= wjB; cc1 *= wjB; cc2 *= wjB;
            float ff0 = wjB * vB0.x;

            cc0 = dpp_add<0xB1>(cc0);  cc1 = dpp_add<0xB1>(cc1);
            cc2 = dpp_add<0xB1>(cc2);  ff0 = dpp_add<0xB1>(ff0);
            cc0 = dpp_add<0x4E>(cc0);  cc1 = dpp_add<0x4E>(cc1);
            cc2 = dpp_add<0x4E>(cc2);  ff0 = dpp_add<0x4E>(ff0);
            cc0 = dpp_add<0x141>(cc0); cc1 = dpp_add<0x141>(cc1);
            cc2 = dpp_add<0x141>(cc2); ff0 = dpp_add<0x141>(ff0);

            if (onB && j < 4) {
                int pi = __float_as_int(b0.w);
                float rv = (j == 0) ? cc0 : (j == 1) ? cc1 : (j == 2) ? cc2
                                                          : fmaxf(ff0, 0.0f);
                size_t a = (j < 3) ? ((size_t)3 * pi + j) : ((size_t)3 * N + pi);
                out[a] = rv;
            }
        }
    }
}

extern "C" void kernel_launch(void* const* d_in, const int* in_sizes, int n_in,
                              void* d_out, int out_size, void* d_ws, size_t ws_size,
                              hipStream_t stream) {
    const float* x     = (const float*)d_in[0];
    const float* d     = (const float*)d_in[1];
    const float* voxel = (const float*)d_in[2];
    float* out = (float*)d_out;
    int N = in_sizes[0] / 3;

    int grid = (N + PTS - 1) / PTS;
    plen_fused_kernel<<<grid, BLK, 0, stream>>>(x, d, voxel, out, N);
}